// Round 4
// baseline (1350.080 us; speedup 1.0000x reference)
//
#include <hip/hip_runtime.h>
#include <math.h>

#define H      1024
#define NA     512
#define NI     256
#define SEQ    4096
#define BATCH  4
#define NTOK   (BATCH*SEQ)      // 16384
#define MTOK   16               // tokens per block
#define CH     4                // h-rows per W chunk
#define NCH    (H / CH)         // 256 chunks
#define PT     20               // token LDS stride (16B-aligned reads, 2-way write conflicts)
#define SINKN  4
#define RECENTN 19
#define MIDN   (SEQ - SINKN - RECENTN)   // 4073
#define KSEL   2025
#define CHK    16

// LDS float offsets
#define WBUF0  0                // [CH][768] chunk buffer 0  (3072 floats)
#define WBUF1  3072             // chunk buffer 1            (3072 floats)
#define KLDS   6144             // [64][PT] keys             (1280 floats)
#define VLDS   7424             // [64][PT] values           (1280 floats)
#define SMEMF  8704             // 34,816 B

// ---------------------------------------------------------------------------
// Kernel 1: fused two-layer MLP scores.
// block = 192 threads (3 waves), 16 tokens/block, 1024 blocks (4 blocks/CU).
// Column-split: wave tt owns unified cols [tt*256, tt*256+256) of 768
// (0..511 = att/W1a, 512..767 = imp/W1i); lane l owns 4 cols (one b128).
// Each wave reads W from LDS once per block (staged cooperatively, double-
// buffered, register-prefetched); tokens are wave-uniform LDS broadcasts.
// ---------------------------------------------------------------------------
__global__ __launch_bounds__(192, 3) void score_kernel(
    const float* __restrict__ keys, const float* __restrict__ values,
    const float* __restrict__ W1a, const float* __restrict__ b1a,
    const float* __restrict__ W2a, const float* __restrict__ b2a,
    const float* __restrict__ W1i, const float* __restrict__ b1i,
    const float* __restrict__ W2i, const float* __restrict__ b2i,
    float* __restrict__ scores)
{
    __shared__ __align__(16) float smem[SMEMF];

    const int tid  = threadIdx.x;
    const int l    = tid & 63;
    const int tt   = tid >> 6;            // wave id 0..2
    const int tokb = blockIdx.x * MTOK;

    float acc[4][16];
#pragma unroll
    for (int j = 0; j < 4; ++j)
#pragma unroll
        for (int t = 0; t < 16; ++t) acc[j][t] = 0.f;

    const float4* W1a4 = (const float4*)W1a;   // [H][128] float4
    const float4* W1i4 = (const float4*)W1i;   // [H][64]  float4

    // ---- token chunk staging (direct): chunk tch covers h in [tch*64, +64) ----
    // 512 float4 total (2 tensors x 16 tok x 16 f4); idx -> (tensor,tok,hq)
    auto stage_tokens = [&](int tch) {
        for (int idx = tid; idx < 512; idx += 192) {
            const int tens = idx >> 8;
            const int tok  = (idx >> 4) & 15;
            const int hq   = idx & 15;
            const float* src = (tens ? values : keys)
                             + (size_t)(tokb + tok) * H + tch * 64 + hq * 4;
            const float4 x = *(const float4*)src;
            float* dst = smem + (tens ? VLDS : KLDS);
            dst[(hq * 4 + 0) * PT + tok] = x.x;
            dst[(hq * 4 + 1) * PT + tok] = x.y;
            dst[(hq * 4 + 2) * PT + tok] = x.z;
            dst[(hq * 4 + 3) * PT + tok] = x.w;
        }
    };

    // ---- W chunk load into regs (4 x float4 per thread) ----
    // LDS float4 slot k*192+tid == [hh=k][col4=tid] of unified [CH][768];
    // cols 0..511 <- W1a row, cols 512..767 <- W1i row. Coalesced.
    auto load_w = [&](int c, float4 w[4]) {
        const int row = c * CH;
#pragma unroll
        for (int k = 0; k < 4; ++k)
            w[k] = (tid < 128) ? W1a4[(size_t)(row + k) * 128 + tid]
                               : W1i4[(size_t)(row + k) * 64 + (tid - 128)];
    };

    // ---- initial stage: W chunk 0 -> buf0, token chunk 0 ----
    {
        float4 w0[4];
        load_w(0, w0);
#pragma unroll
        for (int k = 0; k < 4; ++k) ((float4*)(smem + WBUF0))[k * 192 + tid] = w0[k];
        stage_tokens(0);
    }
    __syncthreads();

    const float* tl = smem + ((tt < 2) ? KLDS : VLDS);

    for (int c = 0; c < NCH; ++c) {
        // prefetch next W chunk into regs (latency hidden under compute)
        float4 wreg[4];
        const bool hw = (c + 1 < NCH);
        if (hw) load_w(c + 1, wreg);

        const float* wb = smem + ((c & 1) ? WBUF1 : WBUF0);
        const int hlb = (c & 15) * CH;    // token-chunk-local h base

#pragma unroll
        for (int hh = 0; hh < CH; ++hh) {
            const int hl = hlb + hh;
            float tokf[16];
            *(float4*)&tokf[0]  = *(const float4*)&tl[hl * PT + 0];
            *(float4*)&tokf[4]  = *(const float4*)&tl[hl * PT + 4];
            *(float4*)&tokf[8]  = *(const float4*)&tl[hl * PT + 8];
            *(float4*)&tokf[12] = *(const float4*)&tl[hl * PT + 12];
            const float4 wv = *(const float4*)&wb[hh * 768 + tt * 256 + (l << 2)];
#pragma unroll
            for (int t = 0; t < 16; ++t) {
                acc[0][t] = fmaf(wv.x, tokf[t], acc[0][t]);
                acc[1][t] = fmaf(wv.y, tokf[t], acc[1][t]);
                acc[2][t] = fmaf(wv.z, tokf[t], acc[2][t]);
                acc[3][t] = fmaf(wv.w, tokf[t], acc[3][t]);
            }
        }

        // write next W chunk into the other buffer (all waves past the
        // previous barrier, so nobody still reads it), then one barrier
        if (hw) {
            float4* wdst = (float4*)(smem + (((c + 1) & 1) ? WBUF1 : WBUF0));
#pragma unroll
            for (int k = 0; k < 4; ++k) wdst[k * 192 + tid] = wreg[k];
        }
        __syncthreads();

        // token chunk boundary: stage next 64 h of tokens (every 16 chunks)
        if ((c & 15) == 15 && c + 1 < NCH) {
            stage_tokens((c >> 4) + 1);
            __syncthreads();
        }
    }

    // ---- epilogue: second layers ----
    float4 b1v, w2v;
    if (tt < 2) {
        b1v = *(const float4*)(b1a + tt * 256 + (l << 2));
        w2v = *(const float4*)(W2a + tt * 256 + (l << 2));
    } else {
        b1v = *(const float4*)(b1i + (l << 2));
        w2v = *(const float4*)(W2i + (l << 2));
    }
    float* red = smem;                    // [16][200] = 3200 floats
#pragma unroll
    for (int t = 0; t < 16; ++t) {
        const float p = fmaxf(acc[0][t] + b1v.x, 0.f) * w2v.x
                      + fmaxf(acc[1][t] + b1v.y, 0.f) * w2v.y
                      + fmaxf(acc[2][t] + b1v.z, 0.f) * w2v.z
                      + fmaxf(acc[3][t] + b1v.w, 0.f) * w2v.w;
        red[t * 200 + tid] = p;
    }
    __syncthreads();
    if (tid < MTOK) {
        float sa = 0.f, si = 0.f;
        for (int i = 0; i < 128; ++i) sa += red[tid * 200 + i];
        for (int i = 128; i < 192; ++i) si += red[tid * 200 + i];
        const float att = 1.f / (1.f + expf(-(sa + b2a[0])));
        scores[tokb + tid] = 0.6f * att + 0.4f * (si + b2i[0]);
    }
}

// ---------------------------------------------------------------------------
// block-wide sum (256 threads), result broadcast to all threads
// ---------------------------------------------------------------------------
__device__ __forceinline__ int block_sum(int val, int* red, int tid)
{
#pragma unroll
    for (int off = 32; off > 0; off >>= 1) val += __shfl_down(val, off);
    if ((tid & 63) == 0) red[tid >> 6] = val;
    __syncthreads();
    const int total = red[0] + red[1] + red[2] + red[3];
    __syncthreads();
    return total;
}

// ---------------------------------------------------------------------------
// Kernel 2: per-row exact top-KSEL of the 4073 middle scores -> float mask.
// 4-pass byte-radix select (256-bin LDS histogram) on sign-flipped uint keys;
// ties kept lowest-index first (top_k semantics). One block per batch row.
// ---------------------------------------------------------------------------
__global__ __launch_bounds__(256) void select_kernel(
    const float* __restrict__ scores, float* __restrict__ mask)
{
    __shared__ unsigned int ks[MIDN];
    __shared__ int hist[256];
    __shared__ int red[4];
    __shared__ int scan_s[256];
    __shared__ unsigned int sh_pref;
    __shared__ int sh_r;

    const int tid = threadIdx.x;
    const int row = blockIdx.x;
    const float* sr = scores + row * SEQ;

    for (int i = tid; i < MIDN; i += 256) {
        unsigned int u = __float_as_uint(sr[SINKN + i]);
        u = (u & 0x80000000u) ? ~u : (u | 0x80000000u);   // order-preserving map
        ks[i] = u;
    }
    if (tid == 0) { sh_pref = 0u; sh_r = KSEL; }
    __syncthreads();

    for (int b = 3; b >= 0; --b) {
        hist[tid] = 0;
        __syncthreads();
        const unsigned int hi_mask = (b == 3) ? 0u : (0xFFFFFFFFu << ((b + 1) * 8));
        const unsigned int pref = sh_pref;
        for (int i = tid; i < MIDN; i += 256) {
            const unsigned int u = ks[i];
            if ((u & hi_mask) == pref)
                atomicAdd(&hist[(u >> (b * 8)) & 255], 1);
        }
        __syncthreads();
        if (tid == 0) {
            int r = sh_r, cum = 0, d = 255;
            for (; d >= 0; --d) {
                cum += hist[d];
                if (cum >= r) break;
            }
            sh_r = r - (cum - hist[d]);
            sh_pref = sh_pref | ((unsigned int)d << (b * 8));
        }
        __syncthreads();
    }
    const unsigned int v = sh_pref;

    const int st = tid * CHK;
    const int en = (st + CHK < MIDN) ? (st + CHK) : MIDN;

    int cgt = 0, ceq = 0;
    for (int k = st; k < en; ++k) { cgt += (ks[k] > v) ? 1 : 0; ceq += (ks[k] == v) ? 1 : 0; }
    const int total_gt = block_sum(cgt, red, tid);
    const int need = KSEL - total_gt;

    scan_s[tid] = ceq;
    __syncthreads();
    if (tid == 0) {
        int run = 0;
        for (int i = 0; i < 256; ++i) { const int t = scan_s[i]; scan_s[i] = run; run += t; }
    }
    __syncthreads();

    float* mr = mask + row * SEQ;
    int r = scan_s[tid];
    for (int k = st; k < en; ++k) {
        const unsigned int u = ks[k];
        bool keep = false;
        if (u > v) keep = true;
        else if (u == v) { keep = (r < need); ++r; }
        mr[SINKN + k] = keep ? 1.f : 0.f;
    }
    for (int s = tid; s < SEQ; s += 256) {
        if (s < SINKN || s >= SEQ - RECENTN) mr[s] = 1.f;
    }
}

// ---------------------------------------------------------------------------
// Kernel 3: out = concat(keys*mask, values*mask), float4 grid-stride.
// ---------------------------------------------------------------------------
__global__ __launch_bounds__(256) void apply_kernel(
    const float* __restrict__ keys, const float* __restrict__ values,
    const float* __restrict__ mask, float* __restrict__ out)
{
    const int QT = NTOK * H / 4;
    const int stride = gridDim.x * 256;
    for (int i4 = blockIdx.x * 256 + threadIdx.x; i4 < 2 * QT; i4 += stride) {
        const bool isv = (i4 >= QT);
        const int  j4  = isv ? (i4 - QT) : i4;
        const float m  = mask[j4 >> 8];
        const float4* src = isv ? (const float4*)values : (const float4*)keys;
        const float4 x = src[j4];
        float4 y; y.x = x.x * m; y.y = x.y * m; y.z = x.z * m; y.w = x.w * m;
        ((float4*)out)[i4] = y;
    }
}

extern "C" void kernel_launch(void* const* d_in, const int* in_sizes, int n_in,
                              void* d_out, int out_size, void* d_ws, size_t ws_size,
                              hipStream_t stream)
{
    const float* keys   = (const float*)d_in[0];
    const float* values = (const float*)d_in[1];
    const float* W1a = (const float*)d_in[2];
    const float* b1a = (const float*)d_in[3];
    const float* W2a = (const float*)d_in[4];
    const float* b2a = (const float*)d_in[5];
    const float* W1i = (const float*)d_in[6];
    const float* b1i = (const float*)d_in[7];
    const float* W2i = (const float*)d_in[8];
    const float* b2i = (const float*)d_in[9];

    float* scores = (float*)d_ws;          // NTOK floats
    float* mask   = scores + NTOK;         // NTOK floats

    score_kernel<<<NTOK / MTOK, 192, 0, stream>>>(keys, values, W1a, b1a, W2a, b2a,
                                                  W1i, b1i, W2i, b2i, scores);
    select_kernel<<<BATCH, 256, 0, stream>>>(scores, mask);
    apply_kernel<<<8192, 256, 0, stream>>>(keys, values, mask, (float*)d_out);
}

// Round 5
// 824.825 us; speedup vs baseline: 1.6368x; 1.6368x over previous
//
#include <hip/hip_runtime.h>
#include <math.h>

#define H      1024
#define NA     512
#define NI     256
#define SEQ    4096
#define BATCH  4
#define NTOK   (BATCH*SEQ)      // 16384
#define MTOK   16               // tokens per block
#define TCH    64               // h-rows per token chunk
#define PT     20               // token LDS stride (16B-aligned reads)
#define SINKN  4
#define RECENTN 19
#define MIDN   (SEQ - SINKN - RECENTN)   // 4073
#define KSEL   2025
#define CHK    16

// LDS float offsets (reused: staging vs epilogue, separated by barriers)
#define KLDS   0                // [64][PT] keys     (1280 floats)
#define VLDS   1280             // [64][PT] values   (1280 floats)
#define REDA   0                // [16][132] att partials (2112 floats)
#define REDI   2112             // [16][68]  imp partials (1088 floats)
#define SMEMF  3200             // 12.8 KB

// ---------------------------------------------------------------------------
// Kernel 1: fused two-layer MLP scores.
// block = 384 threads (6 waves), 16 tokens/block, 1024 blocks.
// Wave w: slab s=w>>1 (256 unified cols: s<2 -> W1a cols s*256.., s==2 ->
// W1i), token-half p=w&1 (tokens p*8..p*8+7). Lane owns 4 cols.
// acc[4][8]=32 VGPRs (spill-safe). W read directly from global, one
// coalesced b128 per wave per h (1 KB, L1-shared between the slab's 2
// waves). Tokens: LDS transposed [h][tok], broadcast b128 reads.
// ---------------------------------------------------------------------------
__global__ __launch_bounds__(384, 5) void score_kernel(
    const float* __restrict__ keys, const float* __restrict__ values,
    const float* __restrict__ W1a, const float* __restrict__ b1a,
    const float* __restrict__ W2a, const float* __restrict__ b2a,
    const float* __restrict__ W1i, const float* __restrict__ b1i,
    const float* __restrict__ W2i, const float* __restrict__ b2i,
    float* __restrict__ scores)
{
    __shared__ __align__(16) float smem[SMEMF];

    const int tid  = threadIdx.x;
    const int l    = tid & 63;
    const int w    = tid >> 6;            // wave 0..5
    const int s    = w >> 1;              // slab 0..2
    const int p    = w & 1;               // token half
    const int tokb = blockIdx.x * MTOK;

    float acc[4][8];
#pragma unroll
    for (int c = 0; c < 4; ++c)
#pragma unroll
        for (int t = 0; t < 8; ++t) acc[c][t] = 0.f;

    const float* wbase;
    int wstr;
    if (s < 2) { wbase = W1a + s * 256 + (l << 2); wstr = NA; }
    else       { wbase = W1i + (l << 2);           wstr = NI; }

    const float* tl = smem + ((s < 2) ? KLDS : VLDS);

    for (int tc = 0; tc < 16; ++tc) {
        if (tc) __syncthreads();
        // stage token chunk tc: 2 tensors x 16 tok x 16 f4 = 512 f4
        for (int idx = tid; idx < 512; idx += 384) {
            const int tens = idx >> 8;
            const int tok  = (idx >> 4) & 15;
            const int hq   = idx & 15;
            const float4 x = *(const float4*)((tens ? values : keys)
                             + (size_t)(tokb + tok) * H + tc * TCH + hq * 4);
            float* dst = smem + (tens ? VLDS : KLDS);
            dst[(hq * 4 + 0) * PT + tok] = x.x;
            dst[(hq * 4 + 1) * PT + tok] = x.y;
            dst[(hq * 4 + 2) * PT + tok] = x.z;
            dst[(hq * 4 + 3) * PT + tok] = x.w;
        }
        __syncthreads();

        const float* wp = wbase + (size_t)tc * TCH * wstr;
#pragma unroll 4
        for (int hl = 0; hl < TCH; ++hl) {
            float t8[8];
            *(float4*)&t8[0] = *(const float4*)&tl[hl * PT + p * 8];
            *(float4*)&t8[4] = *(const float4*)&tl[hl * PT + p * 8 + 4];
            const float4 wv = *(const float4*)(wp + (size_t)hl * wstr);
#pragma unroll
            for (int t = 0; t < 8; ++t) {
                acc[0][t] = fmaf(wv.x, t8[t], acc[0][t]);
                acc[1][t] = fmaf(wv.y, t8[t], acc[1][t]);
                acc[2][t] = fmaf(wv.z, t8[t], acc[2][t]);
                acc[3][t] = fmaf(wv.w, t8[t], acc[3][t]);
            }
        }
    }

    // ---- epilogue: second layers ----
    float4 b1v, w2v;
    if (s < 2) {
        b1v = *(const float4*)(b1a + s * 256 + (l << 2));
        w2v = *(const float4*)(W2a + s * 256 + (l << 2));
    } else {
        b1v = *(const float4*)(b1i + (l << 2));
        w2v = *(const float4*)(W2i + (l << 2));
    }
    __syncthreads();                      // staging LDS free for reuse
#pragma unroll
    for (int t = 0; t < 8; ++t) {
        const float pz = fmaxf(acc[0][t] + b1v.x, 0.f) * w2v.x
                       + fmaxf(acc[1][t] + b1v.y, 0.f) * w2v.y
                       + fmaxf(acc[2][t] + b1v.z, 0.f) * w2v.z
                       + fmaxf(acc[3][t] + b1v.w, 0.f) * w2v.w;
        const int tg = p * 8 + t;
        if (s < 2) smem[REDA + tg * 132 + s * 64 + l] = pz;
        else       smem[REDI + tg * 68 + l] = pz;
    }
    __syncthreads();
    if (tid < MTOK) {
        float sa = 0.f, si = 0.f;
        for (int i = 0; i < 128; ++i) sa += smem[REDA + tid * 132 + i];
        for (int i = 0; i < 64; ++i)  si += smem[REDI + tid * 68 + i];
        const float att = 1.f / (1.f + expf(-(sa + b2a[0])));
        scores[tokb + tid] = 0.6f * att + 0.4f * (si + b2i[0]);
    }
}

// ---------------------------------------------------------------------------
// block-wide sum (256 threads), result broadcast to all threads
// ---------------------------------------------------------------------------
__device__ __forceinline__ int block_sum(int val, int* red, int tid)
{
#pragma unroll
    for (int off = 32; off > 0; off >>= 1) val += __shfl_down(val, off);
    if ((tid & 63) == 0) red[tid >> 6] = val;
    __syncthreads();
    const int total = red[0] + red[1] + red[2] + red[3];
    __syncthreads();
    return total;
}

// ---------------------------------------------------------------------------
// Kernel 2: per-row exact top-KSEL of the 4073 middle scores -> float mask.
// 4-pass byte-radix select (256-bin LDS histogram) on sign-flipped uint keys;
// ties kept lowest-index first (top_k semantics). One block per batch row.
// ---------------------------------------------------------------------------
__global__ __launch_bounds__(256) void select_kernel(
    const float* __restrict__ scores, float* __restrict__ mask)
{
    __shared__ unsigned int ks[MIDN];
    __shared__ int hist[256];
    __shared__ int red[4];
    __shared__ int scan_s[256];
    __shared__ unsigned int sh_pref;
    __shared__ int sh_r;

    const int tid = threadIdx.x;
    const int row = blockIdx.x;
    const float* sr = scores + row * SEQ;

    for (int i = tid; i < MIDN; i += 256) {
        unsigned int u = __float_as_uint(sr[SINKN + i]);
        u = (u & 0x80000000u) ? ~u : (u | 0x80000000u);   // order-preserving map
        ks[i] = u;
    }
    if (tid == 0) { sh_pref = 0u; sh_r = KSEL; }
    __syncthreads();

    for (int b = 3; b >= 0; --b) {
        hist[tid] = 0;
        __syncthreads();
        const unsigned int hi_mask = (b == 3) ? 0u : (0xFFFFFFFFu << ((b + 1) * 8));
        const unsigned int pref = sh_pref;
        for (int i = tid; i < MIDN; i += 256) {
            const unsigned int u = ks[i];
            if ((u & hi_mask) == pref)
                atomicAdd(&hist[(u >> (b * 8)) & 255], 1);
        }
        __syncthreads();
        if (tid == 0) {
            int r = sh_r, cum = 0, d = 255;
            for (; d >= 0; --d) {
                cum += hist[d];
                if (cum >= r) break;
            }
            sh_r = r - (cum - hist[d]);
            sh_pref = sh_pref | ((unsigned int)d << (b * 8));
        }
        __syncthreads();
    }
    const unsigned int v = sh_pref;

    const int st = tid * CHK;
    const int en = (st + CHK < MIDN) ? (st + CHK) : MIDN;

    int cgt = 0, ceq = 0;
    for (int k = st; k < en; ++k) { cgt += (ks[k] > v) ? 1 : 0; ceq += (ks[k] == v) ? 1 : 0; }
    const int total_gt = block_sum(cgt, red, tid);
    const int need = KSEL - total_gt;

    scan_s[tid] = ceq;
    __syncthreads();
    if (tid == 0) {
        int run = 0;
        for (int i = 0; i < 256; ++i) { const int t = scan_s[i]; scan_s[i] = run; run += t; }
    }
    __syncthreads();

    float* mr = mask + row * SEQ;
    int r = scan_s[tid];
    for (int k = st; k < en; ++k) {
        const unsigned int u = ks[k];
        bool keep = false;
        if (u > v) keep = true;
        else if (u == v) { keep = (r < need); ++r; }
        mr[SINKN + k] = keep ? 1.f : 0.f;
    }
    for (int s = tid; s < SEQ; s += 256) {
        if (s < SINKN || s >= SEQ - RECENTN) mr[s] = 1.f;
    }
}

// ---------------------------------------------------------------------------
// Kernel 3: out = concat(keys*mask, values*mask), float4 grid-stride.
// ---------------------------------------------------------------------------
__global__ __launch_bounds__(256) void apply_kernel(
    const float* __restrict__ keys, const float* __restrict__ values,
    const float* __restrict__ mask, float* __restrict__ out)
{
    const int QT = NTOK * H / 4;
    const int stride = gridDim.x * 256;
    for (int i4 = blockIdx.x * 256 + threadIdx.x; i4 < 2 * QT; i4 += stride) {
        const bool isv = (i4 >= QT);
        const int  j4  = isv ? (i4 - QT) : i4;
        const float m  = mask[j4 >> 8];
        const float4* src = isv ? (const float4*)values : (const float4*)keys;
        const float4 x = src[j4];
        float4 y; y.x = x.x * m; y.y = x.y * m; y.z = x.z * m; y.w = x.w * m;
        ((float4*)out)[i4] = y;
    }
}

extern "C" void kernel_launch(void* const* d_in, const int* in_sizes, int n_in,
                              void* d_out, int out_size, void* d_ws, size_t ws_size,
                              hipStream_t stream)
{
    const float* keys   = (const float*)d_in[0];
    const float* values = (const float*)d_in[1];
    const float* W1a = (const float*)d_in[2];
    const float* b1a = (const float*)d_in[3];
    const float* W2a = (const float*)d_in[4];
    const float* b2a = (const float*)d_in[5];
    const float* W1i = (const float*)d_in[6];
    const float* b1i = (const float*)d_in[7];
    const float* W2i = (const float*)d_in[8];
    const float* b2i = (const float*)d_in[9];

    float* scores = (float*)d_ws;          // NTOK floats
    float* mask   = scores + NTOK;         // NTOK floats

    score_kernel<<<NTOK / MTOK, 384, 0, stream>>>(keys, values, W1a, b1a, W2a, b2a,
                                                  W1i, b1i, W2i, b2i, scores);
    select_kernel<<<BATCH, 256, 0, stream>>>(scores, mask);
    apply_kernel<<<8192, 256, 0, stream>>>(keys, values, mask, (float*)d_out);
}